// Round 15
// baseline (3460.052 us; speedup 1.0000x reference)
//
#include <hip/hip_runtime.h>

typedef unsigned short u16;
typedef __attribute__((ext_vector_type(8))) short v8s;
typedef __attribute__((ext_vector_type(4))) float v4f;

__device__ __forceinline__ float b2f(u16 u){
  union { unsigned u32; float f; } c; c.u32 = ((unsigned)u) << 16; return c.f;
}
__device__ __forceinline__ u16 f2b(float f){
  union { float f; unsigned u; } c; c.f = f;
  return (u16)((c.u + 0x7fffu + ((c.u >> 16) & 1u)) >> 16);
}

#define NPAD 46656           // 81*576 padded 9x9 NHWC sample stride
#define NCH 256              // batch chunk (2 chunks)
#define YB_ESTR 802816       // 256*49*64 per-edge ybuf stride

// ---------------- shared GEMM core (128x64 tile, 4 waves, 16x16x32 bf16) ----
__device__ __forceinline__ void gemm_compute(const u16* AS, const u16* BS,
                                             int lane, int wv, v4f acc[2][4]){
  #pragma unroll
  for (int ks = 0; ks < 2; ++ks){
    v8s af[2], bfr[4];
    #pragma unroll
    for (int mr = 0; mr < 2; ++mr){
      int row = wv*32 + mr*16 + (lane & 15);
      int c8 = (ks*4 + (lane >> 4)) ^ (row & 7);
      af[mr] = *(const v8s*)&AS[row*64 + c8*8];
    }
    #pragma unroll
    for (int nr = 0; nr < 4; ++nr){
      int row = nr*16 + (lane & 15);
      int c8 = (ks*4 + (lane >> 4)) ^ (row & 7);
      bfr[nr] = *(const v8s*)&BS[row*64 + c8*8];
    }
    #pragma unroll
    for (int mr = 0; mr < 2; ++mr)
      #pragma unroll
      for (int nr = 0; nr < 4; ++nr)
        acc[mr][nr] = __builtin_amdgcn_mfma_f32_16x16x32_bf16(af[mr], bfr[nr], acc[mr][nr], 0, 0, 0);
  }
}

__device__ __forceinline__ void stage_write(u16* AS, u16* BS, int rA, int c0,
                                            int rB, int sb0, const v8s ra[4], const v8s rb[2]){
  int c8 = c0 >> 3;
  #pragma unroll
  for (int j = 0; j < 4; ++j) *(v8s*)&AS[rA*64 + (((c8 + j) ^ (rA & 7)) << 3)] = ra[j];
  #pragma unroll
  for (int j = 0; j < 2; ++j) *(v8s*)&BS[rB*64 + (((sb0 + j) ^ (rB & 7)) << 3)] = rb[j];
}

// ---------------- conv as implicit GEMM, 256x64 tile, 64x64 wave-tiles -----
// LDS-traffic cut: wave-tile 64x64 -> 8 ds_read_b128 per 16 MFMA (ratio 2.0
// vs 1.33 at 32x64). K order: chunk-outer, tap-slice-inner; reg-staged;
// bijective m204 XCD swizzle.
__global__ __launch_bounds__(256) void k_conv_gemm(
    const u16* __restrict__ src, const u16* __restrict__ wT,
    const float* __restrict__ bias, u16* __restrict__ outp,
    int C, int Ktot, int nstride, int hmul, int wmul, int rowpitch, int steps)
{
  __shared__ u16 As[2][256*64];
  __shared__ u16 Bs[2][64*64];
  const int tid = threadIdx.x;
  const int lane = tid & 63, wv = tid >> 6;

  const int nwg = gridDim.x * gridDim.y;
  int orig = blockIdx.y * gridDim.x + blockIdx.x;
  int q = nwg >> 3, r = nwg & 7;
  int xcd = orig & 7, idx = orig >> 3;
  int swz = (xcd < r ? xcd*(q+1) : r*(q+1) + (xcd - r)*q) + idx;
  const int m0 = (swz / 9) * 256;
  const int cout0 = (swz - (swz/9)*9) * 64;

  // A staging: one row per thread (8 v8s); B: rB = tid>>2 (2 v8s)
  int m = m0 + tid;
  int nI = m / 49, hw = m % 49, h = hw / 7, w = hw % 7;
  const u16* aptr = src + (size_t)nI*nstride + (size_t)(h*hmul + w*wmul)*C;

  const int rB = tid >> 2, sb0 = (tid & 3) << 1;
  const u16* bptr = wT + (size_t)(cout0 + rB)*Ktot + sb0*8;

  v4f acc[4][4];
  v4f vz = {0.f, 0.f, 0.f, 0.f};
  #pragma unroll
  for (int i = 0; i < 4; ++i)
    #pragma unroll
    for (int j = 0; j < 4; ++j) acc[i][j] = vz;

  v8s ra[8], rb[2];
  #pragma unroll
  for (int j = 0; j < 8; ++j) ra[j] = *(const v8s*)(aptr + j*8);
  #pragma unroll
  for (int j = 0; j < 2; ++j) rb[j] = *(const v8s*)(bptr + j*8);
  // stage K-step 0 into buf0
  #pragma unroll
  for (int j = 0; j < 8; ++j)
    *(v8s*)&As[0][tid*64 + ((j ^ (tid & 7)) << 3)] = ra[j];
  #pragma unroll
  for (int j = 0; j < 2; ++j)
    *(v8s*)&Bs[0][rB*64 + (((sb0 + j) ^ (rB & 7)) << 3)] = rb[j];

  for (int s = 0; s < steps; ++s){
    const int buf = s & 1;
    if (s + 1 < steps){
      int s1 = s + 1;
      int chunk = s1 / 9;
      int slice = s1 - chunk*9;
      int kh = slice / 3, kw = slice - kh*3;
      int koffA = (kh*rowpitch + kw)*C + (chunk << 6);
      int koffB = s1 << 6;
      #pragma unroll
      for (int j = 0; j < 8; ++j) ra[j] = *(const v8s*)(aptr + koffA + j*8);
      #pragma unroll
      for (int j = 0; j < 2; ++j) rb[j] = *(const v8s*)(bptr + koffB + j*8);
    }
    __syncthreads();
    // compute: 2 ks x (4 A-frag x 4 B-frag)
    #pragma unroll
    for (int ks = 0; ks < 2; ++ks){
      v8s af[4], bfr[4];
      #pragma unroll
      for (int mr = 0; mr < 4; ++mr){
        int row = wv*64 + mr*16 + (lane & 15);
        int c8 = (ks*4 + (lane >> 4)) ^ (row & 7);
        af[mr] = *(const v8s*)&As[buf][row*64 + c8*8];
      }
      #pragma unroll
      for (int nr = 0; nr < 4; ++nr){
        int row = nr*16 + (lane & 15);
        int c8 = (ks*4 + (lane >> 4)) ^ (row & 7);
        bfr[nr] = *(const v8s*)&Bs[buf][row*64 + c8*8];
      }
      #pragma unroll
      for (int mr = 0; mr < 4; ++mr)
        #pragma unroll
        for (int nr = 0; nr < 4; ++nr)
          acc[mr][nr] = __builtin_amdgcn_mfma_f32_16x16x32_bf16(af[mr], bfr[nr], acc[mr][nr], 0, 0, 0);
    }
    if (s + 1 < steps){
      int nb = buf ^ 1;
      #pragma unroll
      for (int j = 0; j < 8; ++j)
        *(v8s*)&As[nb][tid*64 + ((j ^ (tid & 7)) << 3)] = ra[j];
      #pragma unroll
      for (int j = 0; j < 2; ++j)
        *(v8s*)&Bs[nb][rB*64 + (((sb0 + j) ^ (rB & 7)) << 3)] = rb[j];
    }
  }

  #pragma unroll
  for (int mr = 0; mr < 4; ++mr)
    #pragma unroll
    for (int nr = 0; nr < 4; ++nr)
      #pragma unroll
      for (int ri = 0; ri < 4; ++ri){
        int row = m0 + wv*64 + mr*16 + ((lane >> 4) << 2) + ri;
        int col = cout0 + nr*16 + (lane & 15);
        int n2 = row / 49, hw2 = row % 49, h2 = hw2 / 7, w2 = hw2 % 7;
        float v = acc[mr][nr][ri] + bias[col];
        outp[(size_t)n2*NPAD + (size_t)((h2+1)*9 + (w2+1))*576 + col] = f2b(v);
      }
}

// ---------------- message-pass 1x1 GEMM + segment-sum + base add -----------
__global__ __launch_bounds__(256) void k_pw_gemm(
    const u16* __restrict__ ybuf, const u16* __restrict__ Bp,
    const float* __restrict__ biasp, const u16* __restrict__ basep,
    u16* __restrict__ dst, const int* __restrict__ edlist, int n0)
{
  __shared__ u16 As[2][128*64];
  __shared__ u16 Bs[2][64*64];
  const int tid = threadIdx.x;
  const int m0 = blockIdx.x * 128;
  const int p = blockIdx.y;
  const int lane = tid & 63, wv = tid >> 6;
  const int rA = tid >> 1, c0 = (tid & 1) << 5;
  const int rB = tid >> 2, sb0 = (tid & 3) << 1;
  const u16* aptr = ybuf + (size_t)(m0 + rA)*64 + c0;
  const u16* bptr = Bp + (size_t)(p*64 + rB)*256 + sb0*8;

  v4f acc[2][4];
  v4f vz = {0.f, 0.f, 0.f, 0.f};
  #pragma unroll
  for (int i = 0; i < 2; ++i)
    #pragma unroll
    for (int j = 0; j < 4; ++j) acc[i][j] = vz;

  v8s ra[4], rb[2];
  {
    size_t eoff = (size_t)edlist[p*4] * YB_ESTR;
    #pragma unroll
    for (int j = 0; j < 4; ++j) ra[j] = *(const v8s*)(aptr + eoff + j*8);
    #pragma unroll
    for (int j = 0; j < 2; ++j) rb[j] = *(const v8s*)(bptr + j*8);
  }
  stage_write(&As[0][0], &Bs[0][0], rA, c0, rB, sb0, ra, rb);

  for (int s = 0; s < 4; ++s){
    const int buf = s & 1;
    if (s < 3){
      size_t eoff = (size_t)edlist[p*4 + s + 1] * YB_ESTR;
      int koffB = (s + 1) << 6;
      #pragma unroll
      for (int j = 0; j < 4; ++j) ra[j] = *(const v8s*)(aptr + eoff + j*8);
      #pragma unroll
      for (int j = 0; j < 2; ++j) rb[j] = *(const v8s*)(bptr + koffB + j*8);
    }
    __syncthreads();
    gemm_compute(&As[buf][0], &Bs[buf][0], lane, wv, acc);
    if (s < 3)
      stage_write(&As[(s+1)&1][0], &Bs[(s+1)&1][0], rA, c0, rB, sb0, ra, rb);
  }

  #pragma unroll
  for (int mr = 0; mr < 2; ++mr)
    #pragma unroll
    for (int nr = 0; nr < 4; ++nr)
      #pragma unroll
      for (int ri = 0; ri < 4; ++ri){
        int row = m0 + wv*32 + mr*16 + ((lane >> 4) << 2) + ri;
        int col = nr*16 + (lane & 15);
        int nl = row / 49, hw = row % 49, h = hw / 7, w = hw % 7;
        size_t ad = (size_t)(n0 + nl)*NPAD + (size_t)((h+1)*9 + (w+1))*576 + p*64 + col;
        float v = acc[mr][nr][ri] + biasp[p*64 + col] + b2f(basep[ad]);
        dst[ad] = f2b(v);
      }
}

// ---------------- deconv1 (grouped transposed conv) as parity GEMMs --------
__global__ __launch_bounds__(256) void k_dec1_gemm(
    const u16* __restrict__ src, const u16* __restrict__ B1,
    const float* __restrict__ dbias, u16* __restrict__ dst, int n0)
{
  __shared__ u16 As[2][128*64];
  __shared__ u16 Bs[2][64*64];
  const int tid = threadIdx.x;
  const int m0 = blockIdx.x * 128;
  const int by = blockIdx.y;         // p*4 + parh*2 + parw
  const int p = by >> 2;
  const int parh = (by >> 1) & 1, parw = by & 1;
  const int lane = tid & 63, wv = tid >> 6;
  const int rA = tid >> 1, c0 = (tid & 1) << 5;
  const int rB = tid >> 2, sb0 = (tid & 3) << 1;

  int m = m0 + rA;
  int nl = m / 49, hw = m % 49, mh = hw / 7, mw = hw % 7;
  const u16* aptr = src + (size_t)(n0 + nl)*NPAD
                  + (size_t)((mh + 2 - parh)*9 + (mw + 2 - parw))*576 + p*64 + c0;
  const u16* bptr = B1 + (size_t)(by*64 + rB)*256 + sb0*8;

  v4f acc[2][4];
  v4f vz = {0.f, 0.f, 0.f, 0.f};
  #pragma unroll
  for (int i = 0; i < 2; ++i)
    #pragma unroll
    for (int j = 0; j < 4; ++j) acc[i][j] = vz;

  v8s ra[4], rb[2];
  #pragma unroll
  for (int j = 0; j < 4; ++j) ra[j] = *(const v8s*)(aptr + j*8);
  #pragma unroll
  for (int j = 0; j < 2; ++j) rb[j] = *(const v8s*)(bptr + j*8);
  stage_write(&As[0][0], &Bs[0][0], rA, c0, rB, sb0, ra, rb);

  for (int s = 0; s < 4; ++s){
    const int buf = s & 1;
    if (s < 3){
      int t1 = s + 1;
      int ty = t1 >> 1, tx = t1 & 1;
      int koffA = -(ty*9 + tx)*576;
      int koffB = t1 << 6;
      #pragma unroll
      for (int j = 0; j < 4; ++j) ra[j] = *(const v8s*)(aptr + koffA + j*8);
      #pragma unroll
      for (int j = 0; j < 2; ++j) rb[j] = *(const v8s*)(bptr + koffB + j*8);
    }
    __syncthreads();
    gemm_compute(&As[buf][0], &Bs[buf][0], lane, wv, acc);
    if (s < 3)
      stage_write(&As[(s+1)&1][0], &Bs[(s+1)&1][0], rA, c0, rB, sb0, ra, rb);
  }

  #pragma unroll
  for (int mr = 0; mr < 2; ++mr)
    #pragma unroll
    for (int nr = 0; nr < 4; ++nr)
      #pragma unroll
      for (int ri = 0; ri < 4; ++ri){
        int row = m0 + wv*32 + mr*16 + ((lane >> 4) << 2) + ri;
        int col = nr*16 + (lane & 15);
        int n2 = row / 49, hw2 = row % 49, mh2 = hw2 / 7, mw2 = hw2 % 7;
        int oh = 2*mh2 + 1 - parh, ow = 2*mw2 + 1 - parw;
        float v = acc[mr][nr][ri] + dbias[p*64 + col];
        dst[((size_t)n2*196 + oh*14 + ow)*576 + p*64 + col] = f2b(v);
      }
}

// ---------------- GroupNorm(36)+ReLU, IN PLACE, single-read reg-cached -----
__global__ __launch_bounds__(576) void k_gn0(
    u16* __restrict__ buf, const float* __restrict__ gamma,
    const float* __restrict__ beta)
{
  const int n = blockIdx.x;
  const int t = threadIdx.x;
  const int g = t % 72, ps = t / 72;
  u16* base = buf + (size_t)n*NPAD;
  __shared__ float ss[8][576], sq[8][576];
  __shared__ float csum[576], csq[576];
  __shared__ float smean[36], srstd[36];

  v8s vc[7];
  float s[8], q[8];
  #pragma unroll
  for (int j = 0; j < 8; ++j){ s[j] = 0.f; q[j] = 0.f; }
  #pragma unroll
  for (int it = 0; it < 7; ++it){
    int p2 = ps + it*8;
    if (p2 < 49){
      int h = p2 / 7, w = p2 - h*7;
      vc[it] = *(const v8s*)&base[((h+1)*9 + (w+1))*576 + g*8];
      #pragma unroll
      for (int j = 0; j < 8; ++j){ float f = b2f((u16)vc[it][j]); s[j] += f; q[j] += f*f; }
    }
  }
  #pragma unroll
  for (int j = 0; j < 8; ++j){ ss[ps][g*8 + j] = s[j]; sq[ps][g*8 + j] = q[j]; }
  __syncthreads();
  {
    float cs = 0.f, cq = 0.f;
    #pragma unroll
    for (int i = 0; i < 8; ++i){ cs += ss[i][t]; cq += sq[i][t]; }
    csum[t] = cs; csq[t] = cq;
  }
  __syncthreads();
  if (t < 36){
    float s2 = 0.f, q2 = 0.f;
    for (int j = 0; j < 16; ++j){ s2 += csum[t*16 + j]; q2 += csq[t*16 + j]; }
    float mean = s2 * (1.f/784.f);
    float var = q2 * (1.f/784.f) - mean*mean;
    smean[t] = mean; srstd[t] = rsqrtf(var + 1e-5f);
  }
  __syncthreads();
  float av[8], bv[8];
  #pragma unroll
  for (int j = 0; j < 8; ++j){
    int c0 = g*8 + j, gg = c0 >> 4;
    float a = srstd[gg] * gamma[c0];
    av[j] = a; bv[j] = beta[c0] - smean[gg]*a;
  }
  #pragma unroll
  for (int it = 0; it < 7; ++it){
    int p2 = ps + it*8;
    if (p2 < 49){
      int h = p2 / 7, w = p2 - h*7;
      v8s o;
      #pragma unroll
      for (int j = 0; j < 8; ++j){
        float f = b2f((u16)vc[it][j]) * av[j] + bv[j];
        o[j] = (short)f2b(fmaxf(f, 0.f));
      }
      *(v8s*)&base[((h+1)*9 + (w+1))*576 + g*8] = o;
    }
  }
}

// ---------------- FUSED GroupNorm(9)+ReLU + deconv2 (v2) -------------------
__global__ __launch_bounds__(256) void k_gn1dec2(
    const u16* __restrict__ t_, const float* __restrict__ gamma,
    const float* __restrict__ beta, const float* __restrict__ w2,
    const float* __restrict__ b2, float* __restrict__ outp, int n0)
{
  const int nl = blockIdx.x, p = blockIdx.y;
  const int tid = threadIdx.x;
  const int g = tid & 7, ps = tid >> 3;
  const u16* base = t_ + (size_t)nl*196*576 + p*64 + g*8;
  __shared__ float ss[32][65], sq[32][65];
  __shared__ float stats[2];
  __shared__ u16 xs[256*72];        // pixel stride 72 (144 B) -> banks spread
  __shared__ float ws2[16][64];     // [tap][channel]

  {
    v8s z = {0,0,0,0,0,0,0,0};
    #pragma unroll
    for (int j = 0; j < 9; ++j) *(v8s*)&xs[tid*72 + j*8] = z;
  }
  for (int i = tid; i < 1024; i += 256)
    ws2[i >> 6][i & 63] = w2[(p*64 + (i & 63))*16 + (i >> 6)];

  v8s vc[7];
  float s[8], q[8];
  #pragma unroll
  for (int j = 0; j < 8; ++j){ s[j] = 0.f; q[j] = 0.f; }
  #pragma unroll
  for (int it = 0; it < 7; ++it){
    int i = ps + it*32;
    if (i < 196){
      vc[it] = *(const v8s*)&base[(size_t)i*576];
      #pragma unroll
      for (int j = 0; j < 8; ++j){ float f = b2f((u16)vc[it][j]); s[j] += f; q[j] += f*f; }
    }
  }
  #pragma unroll
  for (int j = 0; j < 8; ++j){ ss[ps][g*8 + j] = s[j]; sq[ps][g*8 + j] = q[j]; }
  __syncthreads();
  if (tid < 64){
    float cs = 0.f, cq = 0.f;
    #pragma unroll
    for (int i = 0; i < 32; ++i){ cs += ss[i][tid]; cq += sq[i][tid]; }
    #pragma unroll
    for (int off = 32; off; off >>= 1){
      cs += __shfl_down(cs, off, 64);
      cq += __shfl_down(cq, off, 64);
    }
    if (tid == 0){
      float mean = cs * (1.f/12544.f);
      float var = cq * (1.f/12544.f) - mean*mean;
      stats[0] = mean; stats[1] = rsqrtf(var + 1e-5f);
    }
  }
  __syncthreads();
  float av[8], bv[8];
  #pragma unroll
  for (int j = 0; j < 8; ++j){
    int c0 = p*64 + g*8 + j;
    float a = stats[1] * gamma[c0];
    av[j] = a; bv[j] = beta[c0] - stats[0]*a;
  }
  #pragma unroll
  for (int it = 0; it < 7; ++it){
    int i = ps + it*32;
    if (i < 196){
      v8s o;
      #pragma unroll
      for (int j = 0; j < 8; ++j){
        float f = b2f((u16)vc[it][j]) * av[j] + bv[j];
        o[j] = (short)f2b(fmaxf(f, 0.f));
      }
      int oh = i / 14, ow = i - oh*14;
      *(v8s*)&xs[((oh+1)*16 + (ow+1))*72 + g*8] = o;
    }
  }
  __syncthreads();

  const int lane = tid & 63, wv = tid >> 6;
  const int lg = lane & 7, lps = lane >> 3;
  const float bias = b2[p];
  #pragma unroll
  for (int par = 0; par < 4; ++par){
    int parh = par >> 1, parw = par & 1;
    float wr[4][8];
    #pragma unroll
    for (int t2 = 0; t2 < 4; ++t2){
      int tap = (parh + 2*(t2 >> 1))*4 + (parw + 2*(t2 & 1));
      #pragma unroll
      for (int j = 0; j < 8; ++j) wr[t2][j] = ws2[tap][lg*8 + j];
    }
    #pragma unroll
    for (int it = 0; it < 7; ++it){
      int oidx = (it*4 + wv)*8 + lps;
      if (oidx < 196){
        int mh = oidx / 14, mw = oidx - mh*14;
        float acc = 0.f;
        #pragma unroll
        for (int t2 = 0; t2 < 4; ++t2){
          int ty = t2 >> 1, tx = t2 & 1;
          int pix = (mh + 2 - parh - ty)*16 + (mw + 2 - parw - tx);
          v8s xv = *(const v8s*)&xs[pix*72 + lg*8];
          #pragma unroll
          for (int j = 0; j < 8; ++j) acc += b2f((u16)xv[j]) * wr[t2][j];
        }
        acc += __shfl_xor(acc, 1, 8);
        acc += __shfl_xor(acc, 2, 8);
        acc += __shfl_xor(acc, 4, 8);
        if (lg == 0){
          int oh2 = 2*mh + 1 - parh, ow2 = 2*mw + 1 - parw;
          outp[((size_t)(n0 + nl)*9 + p)*784 + oh2*28 + ow2] = acc + bias;
        }
      }
    }
  }
}

// ---------------- per-edge depthwise 5x5 (chunked over n) ------------------
__global__ __launch_bounds__(256) void k_dw(
    const u16* __restrict__ src, const float* __restrict__ dww,
    const float* __restrict__ dwb, const int* __restrict__ esrc,
    u16* __restrict__ y, int n0)
{
  const int nl = blockIdx.x, e = blockIdx.y;
  const int q = esrc[e];
  __shared__ u16 xs[81*64];
  __shared__ float wd[64*25];
  for (int i = threadIdx.x; i < 81*8; i += 256){
    int pix = i >> 3, seg = i & 7;
    *(v8s*)&xs[pix*64 + seg*8] =
        *(const v8s*)&src[((size_t)(n0 + nl)*81 + pix)*576 + q*64 + seg*8];
  }
  for (int i = threadIdx.x; i < 1600; i += 256) wd[i] = dww[e*1600 + i];
  __syncthreads();
  for (int oi = threadIdx.x; oi < 3136; oi += 256){
    int c = oi & 63, hw = oi >> 6;
    int h = hw / 7, w = hw % 7;
    float acc = dwb[e*64 + c];
    #pragma unroll
    for (int kh = 0; kh < 5; ++kh){
      int pr = h + kh - 1;
      if (pr < 0 || pr > 8) continue;
      #pragma unroll
      for (int kw = 0; kw < 5; ++kw){
        int pc = w + kw - 1;
        if (pc < 0 || pc > 8) continue;
        acc += b2f(xs[(pr*9 + pc)*64 + c]) * wd[c*25 + kh*5 + kw];
      }
    }
    y[((size_t)(e*NCH + nl)*49 + hw)*64 + c] = f2b(acc);
  }
}

// ---------------- prep kernels ---------------------------------------------
__global__ __launch_bounds__(256) void k_prep_x(const float* __restrict__ x, u16* __restrict__ xpad){
  const int h = blockIdx.x, n = blockIdx.y;
  __shared__ float t[14*257];
  for (int i = threadIdx.x; i < 14*256; i += 256){
    int c = i / 14, w = i % 14;
    t[w*257 + c] = x[(((size_t)n*256 + c)*14 + h)*14 + w];
  }
  __syncthreads();
  for (int i = threadIdx.x; i < 14*256; i += 256){
    int w = i >> 8, c = i & 255;
    xpad[((size_t)n*256 + (h+1)*16 + (w+1))*256 + c] = f2b(t[w*257 + c]);
  }
}

__global__ __launch_bounds__(256) void k_prep_w0(const float* __restrict__ w0, u16* __restrict__ W0T){
  for (size_t i = (size_t)blockIdx.x*256 + threadIdx.x; i < (size_t)576*2304;
       i += (size_t)gridDim.x*256){
    int o = (int)(i / 2304), r = (int)(i % 2304);
    int s = r >> 6, j = r & 63;
    int chunk = s / 9, slice = s - chunk*9;
    int cin = chunk*64 + j;
    W0T[i] = f2b(w0[((size_t)o*256 + cin)*9 + slice]);
  }
}

__global__ __launch_bounds__(256) void k_prep_wc(const float* __restrict__ wc, u16* __restrict__ WcT){
  for (size_t i = (size_t)blockIdx.x*256 + threadIdx.x; i < (size_t)7*576*5184;
       i += (size_t)gridDim.x*256){
    int l = (int)(i / 2985984ull);
    size_t r2 = i % 2985984ull;
    int o = (int)(r2 / 5184), r = (int)(r2 % 5184);
    int s = r >> 6, j = r & 63;
    int chunk = s / 9, slice = s - chunk*9;
    int cin = chunk*64 + j;
    WcT[i] = f2b(wc[(((size_t)(l*576 + o))*576 + cin)*9 + slice]);
  }
}

__global__ __launch_bounds__(256) void k_prep_edges(const int* __restrict__ edst,
    const float* __restrict__ pwb1, const float* __restrict__ pwb2,
    int* __restrict__ edlist, int* __restrict__ ecnt,
    float* __restrict__ bias1, float* __restrict__ bias2){
  __shared__ int cnt[9], lst[36];
  if (threadIdx.x == 0){
    for (int p2 = 0; p2 < 9; ++p2) cnt[p2] = 0;
    for (int e = 0; e < 24; ++e){ int p2 = edst[e]; lst[p2*4 + cnt[p2]] = e; cnt[p2]++; }
    for (int p2 = 0; p2 < 9; ++p2) for (int j = cnt[p2]; j < 4; ++j) lst[p2*4 + j] = 0;
  }
  __syncthreads();
  if (threadIdx.x < 36) edlist[threadIdx.x] = lst[threadIdx.x];
  if (threadIdx.x < 9) ecnt[threadIdx.x] = cnt[threadIdx.x];
  for (int i = threadIdx.x; i < 576; i += 256){
    int p2 = i >> 6, o = i & 63;
    float s1 = 0.f, s2 = 0.f;
    for (int j = 0; j < cnt[p2]; ++j){
      int e = lst[p2*4 + j];
      s1 += pwb1[e*64 + o]; s2 += pwb2[e*64 + o];
    }
    bias1[i] = s1; bias2[i] = s2;
  }
}

__global__ __launch_bounds__(256) void k_prep_pwB(const float* __restrict__ pw1,
    const float* __restrict__ pw2, const int* __restrict__ edlist, const int* __restrict__ ecnt,
    u16* __restrict__ B1, u16* __restrict__ B2){
  for (size_t i = (size_t)blockIdx.x*256 + threadIdx.x; i < (size_t)9*64*256;
       i += (size_t)gridDim.x*256){
    int p = (int)(i >> 14);
    int o = (int)((i >> 8) & 63);
    int k = (int)(i & 255);
    int ei = k >> 6, c = k & 63;
    float v1 = 0.f, v2 = 0.f;
    if (ei < ecnt[p]){
      int e = edlist[p*4 + ei];
      v1 = pw1[(e*64 + o)*64 + c];
      v2 = pw2[(e*64 + o)*64 + c];
    }
    B1[i] = f2b(v1); B2[i] = f2b(v2);
  }
}

__global__ __launch_bounds__(256) void k_prep_decB(const float* __restrict__ dw, u16* __restrict__ DB){
  for (size_t i = (size_t)blockIdx.x*256 + threadIdx.x; i < (size_t)9*4*64*256;
       i += (size_t)gridDim.x*256){
    int c = (int)(i & 63);
    int tt = (int)((i >> 6) & 3);
    int o = (int)((i >> 8) & 63);
    int parp = (int)(i >> 14);
    int par = parp & 3, p = parp >> 2;
    int parh = par >> 1, parw = par & 1, ty = tt >> 1, tx = tt & 1;
    int kh = parh + 2*ty, kw = parw + 2*tx;
    DB[i] = f2b(dw[(((size_t)(p*64 + c))*64 + o)*16 + kh*4 + kw]);
  }
}

__global__ void k_diag(float* o, float a, float b){ o[0] = a; o[1] = b; }

// ---------------- host side ------------------------------------------------
extern "C" void kernel_launch(void* const* d_in, const int* in_sizes, int n_in,
                              void* d_out, int out_size, void* d_ws, size_t ws_size,
                              hipStream_t stream)
{
  (void)in_sizes; (void)n_in; (void)out_size;
  const float* x         = (const float*)d_in[0];
  const float* conv0_w   = (const float*)d_in[1];
  const float* conv0_b   = (const float*)d_in[2];
  const float* convs_w   = (const float*)d_in[3];
  const float* convs_b   = (const float*)d_in[4];
  const float* gn_gamma  = (const float*)d_in[5];
  const float* gn_beta   = (const float*)d_in[6];
  const float* fo_dw_w   = (const float*)d_in[7];
  const float* fo_dw_b   = (const float*)d_in[8];
  const float* fo_pw_w   = (const float*)d_in[9];
  const float* fo_pw_b   = (const float*)d_in[10];
  const float* so_dw_w   = (const float*)d_in[11];
  const float* so_dw_b   = (const float*)d_in[12];
  const float* so_pw_w   = (const float*)d_in[13];
  const float* so_pw_b   = (const float*)d_in[14];
  const float* deconv1_w = (const float*)d_in[15];
  const float* deconv1_b = (const float*)d_in[16];
  const float* gn1_g     = (const float*)d_in[17];
  const float* gn1_b     = (const float*)d_in[18];
  const float* deconv2_w = (const float*)d_in[19];
  const float* deconv2_b = (const float*)d_in[20];
  const int*   edge_src  = (const int*)d_in[21];
  const int*   edge_dst  = (const int*)d_in[22];
  float* outp = (float*)d_out;
  char* ws = (char*)d_ws;

  // ---- workspace layout (aliased) ----
  const size_t SZ_PAD   = (size_t)512*81*576*2;       // 47,775,744
  const size_t SZ_S     = (size_t)512*256*256*2;      // 67,108,864
  const size_t SZ_W0T   = (size_t)576*2304*2;
  const size_t SZ_PWB   = (size_t)9*64*256*2;
  const size_t SZ_DB    = (size_t)9*4*64*256*2;

  size_t o_padA = 0;
  size_t o_padB = o_padA + SZ_PAD;
  size_t o_S    = o_padB + SZ_PAD;
  size_t o_w0t  = o_S    + SZ_S;
  size_t o_b1   = o_w0t  + SZ_W0T;
  size_t o_b2   = o_b1   + SZ_PWB;
  size_t o_db   = o_b2   + SZ_PWB;
  size_t o_bs1  = o_db   + SZ_DB;
  size_t o_bs2  = o_bs1  + 2304;
  size_t o_el   = o_bs2  + 2304;
  size_t total  = o_el   + 256;

  if (ws_size < total){                 // diagnostic: reveal the budget
    k_diag<<<1, 1, 0, stream>>>(outp, (float)ws_size, (float)total);
    return;
  }

  u16* padA  = (u16*)(ws + o_padA);
  u16* padB  = (u16*)(ws + o_padB);
  u16* Sreg  = (u16*)(ws + o_S);
  u16* xpad  = Sreg;                          // prep .. conv0
  u16* WcT   = Sreg;                          // conv1 .. conv7
  u16* ybuf  = Sreg;                          // message passing (38.6 MB/chunk)
  u16* dec1t = Sreg;                          // decode (57.8 MB/chunk)
  u16* W0T   = (u16*)(ws + o_w0t);
  u16* B1    = (u16*)(ws + o_b1);
  u16* B2    = (u16*)(ws + o_b2);
  u16* DB    = (u16*)(ws + o_db);
  float* bs1 = (float*)(ws + o_bs1);
  float* bs2 = (float*)(ws + o_bs2);
  int* elist = (int*)(ws + o_el);
  int* ecnt  = (int*)(ws + o_el + 144);

  // ---- prep ----
  hipMemsetAsync(padA, 0, 2*SZ_PAD, stream);   // padA+padB contiguous
  hipMemsetAsync(Sreg, 0, SZ_S, stream);       // zero borders for xpad

  k_prep_x    <<<dim3(14, 512), 256, 0, stream>>>(x, xpad);
  k_prep_w0   <<<256, 256, 0, stream>>>(conv0_w, W0T);
  k_prep_edges<<<1, 256, 0, stream>>>(edge_dst, fo_pw_b, so_pw_b, elist, ecnt, bs1, bs2);
  k_prep_pwB  <<<64, 256, 0, stream>>>(fo_pw_w, so_pw_w, elist, ecnt, B1, B2);
  k_prep_decB <<<256, 256, 0, stream>>>(deconv1_w, DB);

  // ---- conv0 (stride 2) + GN + ReLU, into padA ----
  k_conv_gemm<<<dim3(98, 9), 256, 0, stream>>>(xpad, W0T, conv0_b, padA,
                                               256, 2304, 65536, 32, 2, 16, 36);
  k_gn0<<<512, 576, 0, stream>>>(padA, gn_gamma, gn_beta);

  // xpad dead -> prep conv weights into the same region
  k_prep_wc<<<1024, 256, 0, stream>>>(convs_w, WcT);

  // ---- 7 stride-1 convs, ping-pong padA/padB, GN in place ----
  for (int l = 0; l < 7; ++l){
    u16* srcp = (l % 2 == 0) ? padA : padB;
    u16* dstp = (l % 2 == 0) ? padB : padA;
    k_conv_gemm<<<dim3(98, 9), 256, 0, stream>>>(srcp, WcT + (size_t)l*2985984,
                                                 convs_b + l*576, dstp,
                                                 576, 5184, NPAD, 9, 1, 9, 81);
    k_gn0<<<512, 576, 0, stream>>>(dstp, gn_gamma + (l+1)*576, gn_beta + (l+1)*576);
  }
  // feat = padB (borders zero), padA free (borders zero)

  // ---- message pass 1: src=feat(padB), base=feat(padB) -> x_fo in padA ----
  for (int c = 0; c < 2; ++c){
    int n0 = c * NCH;
    k_dw     <<<dim3(NCH, 24), 256, 0, stream>>>(padB, fo_dw_w, fo_dw_b, edge_src, ybuf, n0);
    k_pw_gemm<<<dim3(98, 9), 256, 0, stream>>>(ybuf, B1, bs1, padB, padA, elist, n0);
  }
  // ---- message pass 2: src=x_fo(padA), base=feat(padB) -> x_so in padA ----
  for (int c = 0; c < 2; ++c){
    int n0 = c * NCH;
    k_dw     <<<dim3(NCH, 24), 256, 0, stream>>>(padA, so_dw_w, so_dw_b, edge_src, ybuf, n0);
    k_pw_gemm<<<dim3(98, 9), 256, 0, stream>>>(ybuf, B2, bs2, padB, padA, elist, n0);
  }

  // ---- decode fused (x_so = padA) ----
  for (int c = 0; c < 2; ++c){
    int n0 = c * NCH;
    k_dec1_gemm<<<dim3(98, 36), 256, 0, stream>>>(padA, DB, deconv1_b, dec1t, n0);
    k_gn1dec2  <<<dim3(NCH, 9), 256, 0, stream>>>(dec1t, gn1_g, gn1_b,
                                                  deconv2_w, deconv2_b, outp, n0);
  }
  // ---- decode unfused (feat = padB) ----
  for (int c = 0; c < 2; ++c){
    int n0 = c * NCH;
    k_dec1_gemm<<<dim3(98, 36), 256, 0, stream>>>(padB, DB, deconv1_b, dec1t, n0);
    k_gn1dec2  <<<dim3(NCH, 9), 256, 0, stream>>>(dec1t, gn1_g, gn1_b,
                                                  deconv2_w, deconv2_b, outp + 3612672, n0);
  }
}

// Round 16
// 2448.746 us; speedup vs baseline: 1.4130x; 1.4130x over previous
//
#include <hip/hip_runtime.h>

typedef unsigned short u16;
typedef __attribute__((ext_vector_type(8))) short v8s;
typedef __attribute__((ext_vector_type(4))) float v4f;

__device__ __forceinline__ float b2f(u16 u){
  union { unsigned u32; float f; } c; c.u32 = ((unsigned)u) << 16; return c.f;
}
__device__ __forceinline__ u16 f2b(float f){
  union { float f; unsigned u; } c; c.f = f;
  return (u16)((c.u + 0x7fffu + ((c.u >> 16) & 1u)) >> 16);
}

#define NPAD 46656           // 81*576 padded 9x9 NHWC sample stride
#define NCH 256              // batch chunk (2 chunks)
#define YB_ESTR 802816       // 256*49*64 per-edge ybuf stride

// ---------------- shared GEMM core (128x64 tile, 4 waves, 16x16x32 bf16) ----
__device__ __forceinline__ void gemm_compute(const u16* AS, const u16* BS,
                                             int lane, int wv, v4f acc[2][4]){
  #pragma unroll
  for (int ks = 0; ks < 2; ++ks){
    v8s af[2], bfr[4];
    #pragma unroll
    for (int mr = 0; mr < 2; ++mr){
      int row = wv*32 + mr*16 + (lane & 15);
      int c8 = (ks*4 + (lane >> 4)) ^ (row & 7);
      af[mr] = *(const v8s*)&AS[row*64 + c8*8];
    }
    #pragma unroll
    for (int nr = 0; nr < 4; ++nr){
      int row = nr*16 + (lane & 15);
      int c8 = (ks*4 + (lane >> 4)) ^ (row & 7);
      bfr[nr] = *(const v8s*)&BS[row*64 + c8*8];
    }
    #pragma unroll
    for (int mr = 0; mr < 2; ++mr)
      #pragma unroll
      for (int nr = 0; nr < 4; ++nr)
        acc[mr][nr] = __builtin_amdgcn_mfma_f32_16x16x32_bf16(af[mr], bfr[nr], acc[mr][nr], 0, 0, 0);
  }
}

__device__ __forceinline__ void stage_write(u16* AS, u16* BS, int rA, int c0,
                                            int rB, int sb0, const v8s ra[4], const v8s rb[2]){
  int c8 = c0 >> 3;
  #pragma unroll
  for (int j = 0; j < 4; ++j) *(v8s*)&AS[rA*64 + (((c8 + j) ^ (rA & 7)) << 3)] = ra[j];
  #pragma unroll
  for (int j = 0; j < 2; ++j) *(v8s*)&BS[rB*64 + (((sb0 + j) ^ (rB & 7)) << 3)] = rb[j];
}

// ---------------- conv as implicit GEMM (reg-staged + XCD swizzle) ---------
__global__ __launch_bounds__(256) void k_conv_gemm(
    const u16* __restrict__ src, const u16* __restrict__ wT,
    const float* __restrict__ bias, u16* __restrict__ outp,
    int C, int Ktot, int nstride, int hmul, int wmul, int rowpitch, int steps)
{
  __shared__ u16 As[2][128*64];
  __shared__ u16 Bs[2][64*64];
  const int tid = threadIdx.x;
  const int lane = tid & 63, wv = tid >> 6;

  const int nwg = gridDim.x * gridDim.y;
  int orig = blockIdx.y * gridDim.x + blockIdx.x;
  int q = nwg >> 3, r = nwg & 7;
  int xcd = orig & 7, idx = orig >> 3;
  int swz = (xcd < r ? xcd*(q+1) : r*(q+1) + (xcd - r)*q) + idx;
  const int m0 = (swz / 9) * 128;
  const int cout0 = (swz - (swz/9)*9) * 64;

  const int rA = tid >> 1, c0 = (tid & 1) << 5;
  int m = m0 + rA;
  int nI = m / 49, hw = m % 49, h = hw / 7, w = hw % 7;
  const u16* aptr = src + (size_t)nI*nstride + (size_t)(h*hmul + w*wmul)*C + c0;

  const int rB = tid >> 2, sb0 = (tid & 3) << 1;
  const u16* bptr = wT + (size_t)(cout0 + rB)*Ktot + sb0*8;

  v4f acc[2][4];
  v4f vz = {0.f, 0.f, 0.f, 0.f};
  #pragma unroll
  for (int i = 0; i < 2; ++i)
    #pragma unroll
    for (int j = 0; j < 4; ++j) acc[i][j] = vz;

  v8s ra[4], rb[2];
  #pragma unroll
  for (int j = 0; j < 4; ++j) ra[j] = *(const v8s*)(aptr + j*8);
  #pragma unroll
  for (int j = 0; j < 2; ++j) rb[j] = *(const v8s*)(bptr + j*8);
  stage_write(&As[0][0], &Bs[0][0], rA, c0, rB, sb0, ra, rb);

  for (int s = 0; s < steps; ++s){
    const int buf = s & 1;
    if (s + 1 < steps){
      int s1 = s + 1;
      int chunk = s1 / 9;
      int slice = s1 - chunk*9;
      int kh = slice / 3, kw = slice - kh*3;
      int koffA = (kh*rowpitch + kw)*C + (chunk << 6);
      int koffB = s1 << 6;
      #pragma unroll
      for (int j = 0; j < 4; ++j) ra[j] = *(const v8s*)(aptr + koffA + j*8);
      #pragma unroll
      for (int j = 0; j < 2; ++j) rb[j] = *(const v8s*)(bptr + koffB + j*8);
    }
    __syncthreads();
    gemm_compute(&As[buf][0], &Bs[buf][0], lane, wv, acc);
    if (s + 1 < steps)
      stage_write(&As[(s+1)&1][0], &Bs[(s+1)&1][0], rA, c0, rB, sb0, ra, rb);
  }

  #pragma unroll
  for (int mr = 0; mr < 2; ++mr)
    #pragma unroll
    for (int nr = 0; nr < 4; ++nr)
      #pragma unroll
      for (int ri = 0; ri < 4; ++ri){
        int row = m0 + wv*32 + mr*16 + ((lane >> 4) << 2) + ri;
        int col = cout0 + nr*16 + (lane & 15);
        int n2 = row / 49, hw2 = row % 49, h2 = hw2 / 7, w2 = hw2 % 7;
        float v = acc[mr][nr][ri] + bias[col];
        outp[(size_t)n2*NPAD + (size_t)((h2+1)*9 + (w2+1))*576 + col] = f2b(v);
      }
}

// ---------------- message-pass 1x1 GEMM + segment-sum + base add -----------
__global__ __launch_bounds__(256) void k_pw_gemm(
    const u16* __restrict__ ybuf, const u16* __restrict__ Bp,
    const float* __restrict__ biasp, const u16* __restrict__ basep,
    u16* __restrict__ dst, const int* __restrict__ edlist, int n0)
{
  __shared__ u16 As[2][128*64];
  __shared__ u16 Bs[2][64*64];
  const int tid = threadIdx.x;
  const int m0 = blockIdx.x * 128;
  const int p = blockIdx.y;
  const int lane = tid & 63, wv = tid >> 6;
  const int rA = tid >> 1, c0 = (tid & 1) << 5;
  const int rB = tid >> 2, sb0 = (tid & 3) << 1;
  const u16* aptr = ybuf + (size_t)(m0 + rA)*64 + c0;
  const u16* bptr = Bp + (size_t)(p*64 + rB)*256 + sb0*8;

  v4f acc[2][4];
  v4f vz = {0.f, 0.f, 0.f, 0.f};
  #pragma unroll
  for (int i = 0; i < 2; ++i)
    #pragma unroll
    for (int j = 0; j < 4; ++j) acc[i][j] = vz;

  v8s ra[4], rb[2];
  {
    size_t eoff = (size_t)edlist[p*4] * YB_ESTR;
    #pragma unroll
    for (int j = 0; j < 4; ++j) ra[j] = *(const v8s*)(aptr + eoff + j*8);
    #pragma unroll
    for (int j = 0; j < 2; ++j) rb[j] = *(const v8s*)(bptr + j*8);
  }
  stage_write(&As[0][0], &Bs[0][0], rA, c0, rB, sb0, ra, rb);

  for (int s = 0; s < 4; ++s){
    const int buf = s & 1;
    if (s < 3){
      size_t eoff = (size_t)edlist[p*4 + s + 1] * YB_ESTR;
      int koffB = (s + 1) << 6;
      #pragma unroll
      for (int j = 0; j < 4; ++j) ra[j] = *(const v8s*)(aptr + eoff + j*8);
      #pragma unroll
      for (int j = 0; j < 2; ++j) rb[j] = *(const v8s*)(bptr + koffB + j*8);
    }
    __syncthreads();
    gemm_compute(&As[buf][0], &Bs[buf][0], lane, wv, acc);
    if (s < 3)
      stage_write(&As[(s+1)&1][0], &Bs[(s+1)&1][0], rA, c0, rB, sb0, ra, rb);
  }

  #pragma unroll
  for (int mr = 0; mr < 2; ++mr)
    #pragma unroll
    for (int nr = 0; nr < 4; ++nr)
      #pragma unroll
      for (int ri = 0; ri < 4; ++ri){
        int row = m0 + wv*32 + mr*16 + ((lane >> 4) << 2) + ri;
        int col = nr*16 + (lane & 15);
        int nl = row / 49, hw = row % 49, h = hw / 7, w = hw % 7;
        size_t ad = (size_t)(n0 + nl)*NPAD + (size_t)((h+1)*9 + (w+1))*576 + p*64 + col;
        float v = acc[mr][nr][ri] + biasp[p*64 + col] + b2f(basep[ad]);
        dst[ad] = f2b(v);
      }
}

// ---------------- deconv1 (grouped transposed conv) as parity GEMMs --------
__global__ __launch_bounds__(256) void k_dec1_gemm(
    const u16* __restrict__ src, const u16* __restrict__ B1,
    const float* __restrict__ dbias, u16* __restrict__ dst, int n0)
{
  __shared__ u16 As[2][128*64];
  __shared__ u16 Bs[2][64*64];
  const int tid = threadIdx.x;
  const int m0 = blockIdx.x * 128;
  const int by = blockIdx.y;         // p*4 + parh*2 + parw
  const int p = by >> 2;
  const int parh = (by >> 1) & 1, parw = by & 1;
  const int lane = tid & 63, wv = tid >> 6;
  const int rA = tid >> 1, c0 = (tid & 1) << 5;
  const int rB = tid >> 2, sb0 = (tid & 3) << 1;

  int m = m0 + rA;
  int nl = m / 49, hw = m % 49, mh = hw / 7, mw = hw % 7;
  const u16* aptr = src + (size_t)(n0 + nl)*NPAD
                  + (size_t)((mh + 2 - parh)*9 + (mw + 2 - parw))*576 + p*64 + c0;
  const u16* bptr = B1 + (size_t)(by*64 + rB)*256 + sb0*8;

  v4f acc[2][4];
  v4f vz = {0.f, 0.f, 0.f, 0.f};
  #pragma unroll
  for (int i = 0; i < 2; ++i)
    #pragma unroll
    for (int j = 0; j < 4; ++j) acc[i][j] = vz;

  v8s ra[4], rb[2];
  #pragma unroll
  for (int j = 0; j < 4; ++j) ra[j] = *(const v8s*)(aptr + j*8);
  #pragma unroll
  for (int j = 0; j < 2; ++j) rb[j] = *(const v8s*)(bptr + j*8);
  stage_write(&As[0][0], &Bs[0][0], rA, c0, rB, sb0, ra, rb);

  for (int s = 0; s < 4; ++s){
    const int buf = s & 1;
    if (s < 3){
      int t1 = s + 1;
      int ty = t1 >> 1, tx = t1 & 1;
      int koffA = -(ty*9 + tx)*576;
      int koffB = t1 << 6;
      #pragma unroll
      for (int j = 0; j < 4; ++j) ra[j] = *(const v8s*)(aptr + koffA + j*8);
      #pragma unroll
      for (int j = 0; j < 2; ++j) rb[j] = *(const v8s*)(bptr + koffB + j*8);
    }
    __syncthreads();
    gemm_compute(&As[buf][0], &Bs[buf][0], lane, wv, acc);
    if (s < 3)
      stage_write(&As[(s+1)&1][0], &Bs[(s+1)&1][0], rA, c0, rB, sb0, ra, rb);
  }

  #pragma unroll
  for (int mr = 0; mr < 2; ++mr)
    #pragma unroll
    for (int nr = 0; nr < 4; ++nr)
      #pragma unroll
      for (int ri = 0; ri < 4; ++ri){
        int row = m0 + wv*32 + mr*16 + ((lane >> 4) << 2) + ri;
        int col = nr*16 + (lane & 15);
        int n2 = row / 49, hw2 = row % 49, mh2 = hw2 / 7, mw2 = hw2 % 7;
        int oh = 2*mh2 + 1 - parh, ow = 2*mw2 + 1 - parw;
        float v = acc[mr][nr][ri] + dbias[p*64 + col];
        dst[((size_t)n2*196 + oh*14 + ow)*576 + p*64 + col] = f2b(v);
      }
}

// ---------------- GroupNorm(36)+ReLU, IN PLACE, single-read reg-cached -----
__global__ __launch_bounds__(576) void k_gn0(
    u16* __restrict__ buf, const float* __restrict__ gamma,
    const float* __restrict__ beta)
{
  const int n = blockIdx.x;
  const int t = threadIdx.x;
  const int g = t % 72, ps = t / 72;
  u16* base = buf + (size_t)n*NPAD;
  __shared__ float ss[8][576], sq[8][576];
  __shared__ float csum[576], csq[576];
  __shared__ float smean[36], srstd[36];

  v8s vc[7];
  float s[8], q[8];
  #pragma unroll
  for (int j = 0; j < 8; ++j){ s[j] = 0.f; q[j] = 0.f; }
  #pragma unroll
  for (int it = 0; it < 7; ++it){
    int p2 = ps + it*8;
    if (p2 < 49){
      int h = p2 / 7, w = p2 - h*7;
      vc[it] = *(const v8s*)&base[((h+1)*9 + (w+1))*576 + g*8];
      #pragma unroll
      for (int j = 0; j < 8; ++j){ float f = b2f((u16)vc[it][j]); s[j] += f; q[j] += f*f; }
    }
  }
  #pragma unroll
  for (int j = 0; j < 8; ++j){ ss[ps][g*8 + j] = s[j]; sq[ps][g*8 + j] = q[j]; }
  __syncthreads();
  {
    float cs = 0.f, cq = 0.f;
    #pragma unroll
    for (int i = 0; i < 8; ++i){ cs += ss[i][t]; cq += sq[i][t]; }
    csum[t] = cs; csq[t] = cq;
  }
  __syncthreads();
  if (t < 36){
    float s2 = 0.f, q2 = 0.f;
    for (int j = 0; j < 16; ++j){ s2 += csum[t*16 + j]; q2 += csq[t*16 + j]; }
    float mean = s2 * (1.f/784.f);
    float var = q2 * (1.f/784.f) - mean*mean;
    smean[t] = mean; srstd[t] = rsqrtf(var + 1e-5f);
  }
  __syncthreads();
  float av[8], bv[8];
  #pragma unroll
  for (int j = 0; j < 8; ++j){
    int c0 = g*8 + j, gg = c0 >> 4;
    float a = srstd[gg] * gamma[c0];
    av[j] = a; bv[j] = beta[c0] - smean[gg]*a;
  }
  #pragma unroll
  for (int it = 0; it < 7; ++it){
    int p2 = ps + it*8;
    if (p2 < 49){
      int h = p2 / 7, w = p2 - h*7;
      v8s o;
      #pragma unroll
      for (int j = 0; j < 8; ++j){
        float f = b2f((u16)vc[it][j]) * av[j] + bv[j];
        o[j] = (short)f2b(fmaxf(f, 0.f));
      }
      *(v8s*)&base[((h+1)*9 + (w+1))*576 + g*8] = o;
    }
  }
}

// ---------------- FUSED GroupNorm(9)+ReLU + deconv2 (v2) -------------------
__global__ __launch_bounds__(256) void k_gn1dec2(
    const u16* __restrict__ t_, const float* __restrict__ gamma,
    const float* __restrict__ beta, const float* __restrict__ w2,
    const float* __restrict__ b2, float* __restrict__ outp, int n0)
{
  const int nl = blockIdx.x, p = blockIdx.y;
  const int tid = threadIdx.x;
  const int g = tid & 7, ps = tid >> 3;
  const u16* base = t_ + (size_t)nl*196*576 + p*64 + g*8;
  __shared__ float ss[32][65], sq[32][65];
  __shared__ float stats[2];
  __shared__ u16 xs[256*72];        // pixel stride 72 (144 B) -> banks spread
  __shared__ float ws2[16][64];     // [tap][channel]

  {
    v8s z = {0,0,0,0,0,0,0,0};
    #pragma unroll
    for (int j = 0; j < 9; ++j) *(v8s*)&xs[tid*72 + j*8] = z;
  }
  for (int i = tid; i < 1024; i += 256)
    ws2[i >> 6][i & 63] = w2[(p*64 + (i & 63))*16 + (i >> 6)];

  v8s vc[7];
  float s[8], q[8];
  #pragma unroll
  for (int j = 0; j < 8; ++j){ s[j] = 0.f; q[j] = 0.f; }
  #pragma unroll
  for (int it = 0; it < 7; ++it){
    int i = ps + it*32;
    if (i < 196){
      vc[it] = *(const v8s*)&base[(size_t)i*576];
      #pragma unroll
      for (int j = 0; j < 8; ++j){ float f = b2f((u16)vc[it][j]); s[j] += f; q[j] += f*f; }
    }
  }
  #pragma unroll
  for (int j = 0; j < 8; ++j){ ss[ps][g*8 + j] = s[j]; sq[ps][g*8 + j] = q[j]; }
  __syncthreads();
  if (tid < 64){
    float cs = 0.f, cq = 0.f;
    #pragma unroll
    for (int i = 0; i < 32; ++i){ cs += ss[i][tid]; cq += sq[i][tid]; }
    #pragma unroll
    for (int off = 32; off; off >>= 1){
      cs += __shfl_down(cs, off, 64);
      cq += __shfl_down(cq, off, 64);
    }
    if (tid == 0){
      float mean = cs * (1.f/12544.f);
      float var = cq * (1.f/12544.f) - mean*mean;
      stats[0] = mean; stats[1] = rsqrtf(var + 1e-5f);
    }
  }
  __syncthreads();
  float av[8], bv[8];
  #pragma unroll
  for (int j = 0; j < 8; ++j){
    int c0 = p*64 + g*8 + j;
    float a = stats[1] * gamma[c0];
    av[j] = a; bv[j] = beta[c0] - stats[0]*a;
  }
  #pragma unroll
  for (int it = 0; it < 7; ++it){
    int i = ps + it*32;
    if (i < 196){
      v8s o;
      #pragma unroll
      for (int j = 0; j < 8; ++j){
        float f = b2f((u16)vc[it][j]) * av[j] + bv[j];
        o[j] = (short)f2b(fmaxf(f, 0.f));
      }
      int oh = i / 14, ow = i - oh*14;
      *(v8s*)&xs[((oh+1)*16 + (ow+1))*72 + g*8] = o;
    }
  }
  __syncthreads();

  const int lane = tid & 63, wv = tid >> 6;
  const int lg = lane & 7, lps = lane >> 3;
  const float bias = b2[p];
  #pragma unroll
  for (int par = 0; par < 4; ++par){
    int parh = par >> 1, parw = par & 1;
    float wr[4][8];
    #pragma unroll
    for (int t2 = 0; t2 < 4; ++t2){
      int tap = (parh + 2*(t2 >> 1))*4 + (parw + 2*(t2 & 1));
      #pragma unroll
      for (int j = 0; j < 8; ++j) wr[t2][j] = ws2[tap][lg*8 + j];
    }
    #pragma unroll
    for (int it = 0; it < 7; ++it){
      int oidx = (it*4 + wv)*8 + lps;
      if (oidx < 196){
        int mh = oidx / 14, mw = oidx - mh*14;
        float acc = 0.f;
        #pragma unroll
        for (int t2 = 0; t2 < 4; ++t2){
          int ty = t2 >> 1, tx = t2 & 1;
          int pix = (mh + 2 - parh - ty)*16 + (mw + 2 - parw - tx);
          v8s xv = *(const v8s*)&xs[pix*72 + lg*8];
          #pragma unroll
          for (int j = 0; j < 8; ++j) acc += b2f((u16)xv[j]) * wr[t2][j];
        }
        acc += __shfl_xor(acc, 1, 8);
        acc += __shfl_xor(acc, 2, 8);
        acc += __shfl_xor(acc, 4, 8);
        if (lg == 0){
          int oh2 = 2*mh + 1 - parh, ow2 = 2*mw + 1 - parw;
          outp[((size_t)(n0 + nl)*9 + p)*784 + oh2*28 + ow2] = acc + bias;
        }
      }
    }
  }
}

// ---------------- per-edge depthwise 5x5 (chunked over n) ------------------
__global__ __launch_bounds__(256) void k_dw(
    const u16* __restrict__ src, const float* __restrict__ dww,
    const float* __restrict__ dwb, const int* __restrict__ esrc,
    u16* __restrict__ y, int n0)
{
  const int nl = blockIdx.x, e = blockIdx.y;
  const int q = esrc[e];
  __shared__ u16 xs[81*64];
  __shared__ float wd[64*25];
  for (int i = threadIdx.x; i < 81*8; i += 256){
    int pix = i >> 3, seg = i & 7;
    *(v8s*)&xs[pix*64 + seg*8] =
        *(const v8s*)&src[((size_t)(n0 + nl)*81 + pix)*576 + q*64 + seg*8];
  }
  for (int i = threadIdx.x; i < 1600; i += 256) wd[i] = dww[e*1600 + i];
  __syncthreads();
  for (int oi = threadIdx.x; oi < 3136; oi += 256){
    int c = oi & 63, hw = oi >> 6;
    int h = hw / 7, w = hw % 7;
    float acc = dwb[e*64 + c];
    #pragma unroll
    for (int kh = 0; kh < 5; ++kh){
      int pr = h + kh - 1;
      if (pr < 0 || pr > 8) continue;
      #pragma unroll
      for (int kw = 0; kw < 5; ++kw){
        int pc = w + kw - 1;
        if (pc < 0 || pc > 8) continue;
        acc += b2f(xs[(pr*9 + pc)*64 + c]) * wd[c*25 + kh*5 + kw];
      }
    }
    y[((size_t)(e*NCH + nl)*49 + hw)*64 + c] = f2b(acc);
  }
}

// ---------------- prep kernels ---------------------------------------------
__global__ __launch_bounds__(256) void k_prep_x(const float* __restrict__ x, u16* __restrict__ xpad){
  const int h = blockIdx.x, n = blockIdx.y;
  __shared__ float t[14*257];
  for (int i = threadIdx.x; i < 14*256; i += 256){
    int c = i / 14, w = i % 14;
    t[w*257 + c] = x[(((size_t)n*256 + c)*14 + h)*14 + w];
  }
  __syncthreads();
  for (int i = threadIdx.x; i < 14*256; i += 256){
    int w = i >> 8, c = i & 255;
    xpad[((size_t)n*256 + (h+1)*16 + (w+1))*256 + c] = f2b(t[w*257 + c]);
  }
}

__global__ __launch_bounds__(256) void k_prep_w0(const float* __restrict__ w0, u16* __restrict__ W0T){
  for (size_t i = (size_t)blockIdx.x*256 + threadIdx.x; i < (size_t)576*2304;
       i += (size_t)gridDim.x*256){
    int o = (int)(i / 2304), r = (int)(i % 2304);
    int s = r >> 6, j = r & 63;
    int chunk = s / 9, slice = s - chunk*9;
    int cin = chunk*64 + j;
    W0T[i] = f2b(w0[((size_t)o*256 + cin)*9 + slice]);
  }
}

__global__ __launch_bounds__(256) void k_prep_wc(const float* __restrict__ wc, u16* __restrict__ WcT){
  for (size_t i = (size_t)blockIdx.x*256 + threadIdx.x; i < (size_t)7*576*5184;
       i += (size_t)gridDim.x*256){
    int l = (int)(i / 2985984ull);
    size_t r2 = i % 2985984ull;
    int o = (int)(r2 / 5184), r = (int)(r2 % 5184);
    int s = r >> 6, j = r & 63;
    int chunk = s / 9, slice = s - chunk*9;
    int cin = chunk*64 + j;
    WcT[i] = f2b(wc[(((size_t)(l*576 + o))*576 + cin)*9 + slice]);
  }
}

__global__ __launch_bounds__(256) void k_prep_edges(const int* __restrict__ edst,
    const float* __restrict__ pwb1, const float* __restrict__ pwb2,
    int* __restrict__ edlist, int* __restrict__ ecnt,
    float* __restrict__ bias1, float* __restrict__ bias2){
  __shared__ int cnt[9], lst[36];
  if (threadIdx.x == 0){
    for (int p2 = 0; p2 < 9; ++p2) cnt[p2] = 0;
    for (int e = 0; e < 24; ++e){ int p2 = edst[e]; lst[p2*4 + cnt[p2]] = e; cnt[p2]++; }
    for (int p2 = 0; p2 < 9; ++p2) for (int j = cnt[p2]; j < 4; ++j) lst[p2*4 + j] = 0;
  }
  __syncthreads();
  if (threadIdx.x < 36) edlist[threadIdx.x] = lst[threadIdx.x];
  if (threadIdx.x < 9) ecnt[threadIdx.x] = cnt[threadIdx.x];
  for (int i = threadIdx.x; i < 576; i += 256){
    int p2 = i >> 6, o = i & 63;
    float s1 = 0.f, s2 = 0.f;
    for (int j = 0; j < cnt[p2]; ++j){
      int e = lst[p2*4 + j];
      s1 += pwb1[e*64 + o]; s2 += pwb2[e*64 + o];
    }
    bias1[i] = s1; bias2[i] = s2;
  }
}

__global__ __launch_bounds__(256) void k_prep_pwB(const float* __restrict__ pw1,
    const float* __restrict__ pw2, const int* __restrict__ edlist, const int* __restrict__ ecnt,
    u16* __restrict__ B1, u16* __restrict__ B2){
  for (size_t i = (size_t)blockIdx.x*256 + threadIdx.x; i < (size_t)9*64*256;
       i += (size_t)gridDim.x*256){
    int p = (int)(i >> 14);
    int o = (int)((i >> 8) & 63);
    int k = (int)(i & 255);
    int ei = k >> 6, c = k & 63;
    float v1 = 0.f, v2 = 0.f;
    if (ei < ecnt[p]){
      int e = edlist[p*4 + ei];
      v1 = pw1[(e*64 + o)*64 + c];
      v2 = pw2[(e*64 + o)*64 + c];
    }
    B1[i] = f2b(v1); B2[i] = f2b(v2);
  }
}

__global__ __launch_bounds__(256) void k_prep_decB(const float* __restrict__ dw, u16* __restrict__ DB){
  for (size_t i = (size_t)blockIdx.x*256 + threadIdx.x; i < (size_t)9*4*64*256;
       i += (size_t)gridDim.x*256){
    int c = (int)(i & 63);
    int tt = (int)((i >> 6) & 3);
    int o = (int)((i >> 8) & 63);
    int parp = (int)(i >> 14);
    int par = parp & 3, p = parp >> 2;
    int parh = par >> 1, parw = par & 1, ty = tt >> 1, tx = tt & 1;
    int kh = parh + 2*ty, kw = parw + 2*tx;
    DB[i] = f2b(dw[(((size_t)(p*64 + c))*64 + o)*16 + kh*4 + kw]);
  }
}

__global__ void k_diag(float* o, float a, float b){ o[0] = a; o[1] = b; }

// ---------------- host side ------------------------------------------------
extern "C" void kernel_launch(void* const* d_in, const int* in_sizes, int n_in,
                              void* d_out, int out_size, void* d_ws, size_t ws_size,
                              hipStream_t stream)
{
  (void)in_sizes; (void)n_in; (void)out_size;
  const float* x         = (const float*)d_in[0];
  const float* conv0_w   = (const float*)d_in[1];
  const float* conv0_b   = (const float*)d_in[2];
  const float* convs_w   = (const float*)d_in[3];
  const float* convs_b   = (const float*)d_in[4];
  const float* gn_gamma  = (const float*)d_in[5];
  const float* gn_beta   = (const float*)d_in[6];
  const float* fo_dw_w   = (const float*)d_in[7];
  const float* fo_dw_b   = (const float*)d_in[8];
  const float* fo_pw_w   = (const float*)d_in[9];
  const float* fo_pw_b   = (const float*)d_in[10];
  const float* so_dw_w   = (const float*)d_in[11];
  const float* so_dw_b   = (const float*)d_in[12];
  const float* so_pw_w   = (const float*)d_in[13];
  const float* so_pw_b   = (const float*)d_in[14];
  const float* deconv1_w = (const float*)d_in[15];
  const float* deconv1_b = (const float*)d_in[16];
  const float* gn1_g     = (const float*)d_in[17];
  const float* gn1_b     = (const float*)d_in[18];
  const float* deconv2_w = (const float*)d_in[19];
  const float* deconv2_b = (const float*)d_in[20];
  const int*   edge_src  = (const int*)d_in[21];
  const int*   edge_dst  = (const int*)d_in[22];
  float* outp = (float*)d_out;
  char* ws = (char*)d_ws;

  // ---- workspace layout (aliased) ----
  const size_t SZ_PAD   = (size_t)512*81*576*2;       // 47,775,744
  const size_t SZ_S     = (size_t)512*256*256*2;      // 67,108,864
  const size_t SZ_W0T   = (size_t)576*2304*2;
  const size_t SZ_PWB   = (size_t)9*64*256*2;
  const size_t SZ_DB    = (size_t)9*4*64*256*2;

  size_t o_padA = 0;
  size_t o_padB = o_padA + SZ_PAD;
  size_t o_S    = o_padB + SZ_PAD;
  size_t o_w0t  = o_S    + SZ_S;
  size_t o_b1   = o_w0t  + SZ_W0T;
  size_t o_b2   = o_b1   + SZ_PWB;
  size_t o_db   = o_b2   + SZ_PWB;
  size_t o_bs1  = o_db   + SZ_DB;
  size_t o_bs2  = o_bs1  + 2304;
  size_t o_el   = o_bs2  + 2304;
  size_t total  = o_el   + 256;

  if (ws_size < total){                 // diagnostic: reveal the budget
    k_diag<<<1, 1, 0, stream>>>(outp, (float)ws_size, (float)total);
    return;
  }

  u16* padA  = (u16*)(ws + o_padA);
  u16* padB  = (u16*)(ws + o_padB);
  u16* Sreg  = (u16*)(ws + o_S);
  u16* xpad  = Sreg;                          // prep .. conv0
  u16* WcT   = Sreg;                          // conv1 .. conv7
  u16* ybuf  = Sreg;                          // message passing (38.6 MB/chunk)
  u16* dec1t = Sreg;                          // decode (57.8 MB/chunk)
  u16* W0T   = (u16*)(ws + o_w0t);
  u16* B1    = (u16*)(ws + o_b1);
  u16* B2    = (u16*)(ws + o_b2);
  u16* DB    = (u16*)(ws + o_db);
  float* bs1 = (float*)(ws + o_bs1);
  float* bs2 = (float*)(ws + o_bs2);
  int* elist = (int*)(ws + o_el);
  int* ecnt  = (int*)(ws + o_el + 144);

  // ---- prep ----
  hipMemsetAsync(padA, 0, 2*SZ_PAD, stream);   // padA+padB contiguous
  hipMemsetAsync(Sreg, 0, SZ_S, stream);       // zero borders for xpad

  k_prep_x    <<<dim3(14, 512), 256, 0, stream>>>(x, xpad);
  k_prep_w0   <<<256, 256, 0, stream>>>(conv0_w, W0T);
  k_prep_edges<<<1, 256, 0, stream>>>(edge_dst, fo_pw_b, so_pw_b, elist, ecnt, bs1, bs2);
  k_prep_pwB  <<<64, 256, 0, stream>>>(fo_pw_w, so_pw_w, elist, ecnt, B1, B2);
  k_prep_decB <<<256, 256, 0, stream>>>(deconv1_w, DB);

  // ---- conv0 (stride 2) + GN + ReLU, into padA ----
  k_conv_gemm<<<dim3(196, 9), 256, 0, stream>>>(xpad, W0T, conv0_b, padA,
                                                256, 2304, 65536, 32, 2, 16, 36);
  k_gn0<<<512, 576, 0, stream>>>(padA, gn_gamma, gn_beta);

  // xpad dead -> prep conv weights into the same region
  k_prep_wc<<<1024, 256, 0, stream>>>(convs_w, WcT);

  // ---- 7 stride-1 convs, ping-pong padA/padB, GN in place ----
  for (int l = 0; l < 7; ++l){
    u16* srcp = (l % 2 == 0) ? padA : padB;
    u16* dstp = (l % 2 == 0) ? padB : padA;
    k_conv_gemm<<<dim3(196, 9), 256, 0, stream>>>(srcp, WcT + (size_t)l*2985984,
                                                  convs_b + l*576, dstp,
                                                  576, 5184, NPAD, 9, 1, 9, 81);
    k_gn0<<<512, 576, 0, stream>>>(dstp, gn_gamma + (l+1)*576, gn_beta + (l+1)*576);
  }
  // feat = padB (borders zero), padA free (borders zero)

  // ---- message pass 1: src=feat(padB), base=feat(padB) -> x_fo in padA ----
  for (int c = 0; c < 2; ++c){
    int n0 = c * NCH;
    k_dw     <<<dim3(NCH, 24), 256, 0, stream>>>(padB, fo_dw_w, fo_dw_b, edge_src, ybuf, n0);
    k_pw_gemm<<<dim3(98, 9), 256, 0, stream>>>(ybuf, B1, bs1, padB, padA, elist, n0);
  }
  // ---- message pass 2: src=x_fo(padA), base=feat(padB) -> x_so in padA ----
  for (int c = 0; c < 2; ++c){
    int n0 = c * NCH;
    k_dw     <<<dim3(NCH, 24), 256, 0, stream>>>(padA, so_dw_w, so_dw_b, edge_src, ybuf, n0);
    k_pw_gemm<<<dim3(98, 9), 256, 0, stream>>>(ybuf, B2, bs2, padB, padA, elist, n0);
  }

  // ---- decode fused (x_so = padA) ----
  for (int c = 0; c < 2; ++c){
    int n0 = c * NCH;
    k_dec1_gemm<<<dim3(98, 36), 256, 0, stream>>>(padA, DB, deconv1_b, dec1t, n0);
    k_gn1dec2  <<<dim3(NCH, 9), 256, 0, stream>>>(dec1t, gn1_g, gn1_b,
                                                  deconv2_w, deconv2_b, outp, n0);
  }
  // ---- decode unfused (feat = padB) ----
  for (int c = 0; c < 2; ++c){
    int n0 = c * NCH;
    k_dec1_gemm<<<dim3(98, 36), 256, 0, stream>>>(padB, DB, deconv1_b, dec1t, n0);
    k_gn1dec2  <<<dim3(NCH, 9), 256, 0, stream>>>(dec1t, gn1_g, gn1_b,
                                                  deconv2_w, deconv2_b, outp + 3612672, n0);
  }
}